// Round 7
// baseline (8612.965 us; speedup 1.0000x reference)
//
#include <hip/hip_runtime.h>
#include <cstdint>

// ============================================================================
// EncoderLSTMReal: reverse LSTM (T=200,B=1024,H=512,IN=64) + 2 tanh-MLP heads.
// CONTRACT (R0-R8): inputs fp32 dict order; OUTPUT FLOAT32 (mu 0..32768, lv
// next); heads read fp32 h_final.
// Round-16 (R7): gate-split waves -> 4 waves/SIMD for MLP.
//   R6 post-mortem: step ~35 us vs 3.5 us MFMA floor. Per-step L2 inval =>
//   ~11 MB/step refetch from LLC at ~300 GB/s effective — LATENCY-bound:
//   only 2 waves/SIMD (2048 waves total), ~12 loads in flight per SIMD.
//   Fix: wave = 16r x 16jj x 2 gates (was 4) -> 4096 waves, grid 512 =
//   32 mt x 16 jt, 2 blocks/CU, 4 waves/SIMD, LDS 80 KB (A 2x8KB, B 2x32KB).
//   Cell now needs one sG LDS roundtrip (gates split across waves); sG
//   reuses B0 region after final barrier. Accumulation order BIT-IDENTICAL
//   to R6 (same 3-MFMA split sequence) => absmax 0.00195 expected.
//   wsw/wprep layout unchanged. Same-jt blocks -> same XCD (bid%8=jt%8).
// ws: maxm@0; c_perm/z@512 (aliased); h_final@4260352; wsw@6357504 (4.5MB);
//     bsum@11076096; hhi@11084288; hlo@13181440.
// ============================================================================

typedef _Float16 f16;
typedef __attribute__((ext_vector_type(4))) _Float16 f16x4;
typedef __attribute__((ext_vector_type(8))) _Float16 f16x8;
typedef __attribute__((ext_vector_type(2))) float f32x2;
typedef __attribute__((ext_vector_type(4))) float f32x4;

#define DEV __device__ __forceinline__

DEV float sigf(float x) { return 1.0f / (1.0f + expf(-x)); }

// ============ weight pre-swizzle + bias pre-sum (UNCHANGED from R6) =========
// wsw uint4 idx = ((jt*9 + ch)*32 + Lb)*64 + lane, Lb = ((g*2+jg)*2+ks)*2+p.
// value: 8 halves of plane p of w[n][kb..kb+7], n = g*512+jt*32+jg*16+(lane&15),
// kb = ch*64 + ks*32 + (lane>>4)*8.  (k<64 -> w_ih, else w_hh.)
__global__ void __launch_bounds__(256)
wprep_kernel(const float* __restrict__ w_ih, const float* __restrict__ w_hh,
             uint4* __restrict__ wsw, const float* __restrict__ b_ih,
             const float* __restrict__ b_hh, float* __restrict__ bsum) {
  int idx = blockIdx.x * 256 + threadIdx.x;       // 1152*256 = 294912 exact
  if (idx < 2048) bsum[idx] = b_ih[idx] + b_hh[idx];
  if (idx >= 16 * 9 * 32 * 64) return;
  int jt = idx / 18432, rem = idx - jt * 18432;
  int ch = rem >> 11, r2 = rem & 2047;
  int Lb = r2 >> 6, lane = r2 & 63;
  int p = Lb & 1, ks = (Lb >> 1) & 1, jg = (Lb >> 2) & 1, g = Lb >> 3;
  int n = g * 512 + jt * 32 + jg * 16 + (lane & 15);
  int kb = ch * 64 + ks * 32 + (lane >> 4) * 8;
  f16x8 o;
#pragma unroll
  for (int e = 0; e < 8; e++) {
    int k = kb + e;
    float v = (k < 64) ? w_ih[n * 64 + k] : w_hh[(size_t)n * 512 + (k - 64)];
    f16 hi = (f16)v;
    o[e] = p ? (f16)(v - (float)hi) : hi;
  }
  wsw[idx] = *(uint4*)&o;
}

// ============================ per-step LSTM =================================
// grid 512 = 32 mt x 16 jt; block 512 = 8 waves = (rg 0..1, jg 0..1, gg 0..1).
// wave: rows m0+rg*16..+15, jj = jt*32+jg*16..+15, gates {gg*2, gg*2+1}.
// LDS (uint4): A[cur] @ cur*512 (8 lines x 64), B[cur] @ 1024+cur*2048
// (32 lines x 64). sG (fp32 32x133) reuses B0 region after final barrier.
__global__ void __launch_bounds__(512, 4)
lstm_step(const float* __restrict__ x, const float* __restrict__ a,
          const uint4* __restrict__ wsw, const float* __restrict__ bsum,
          const f16* __restrict__ hhi_in, const f16* __restrict__ hlo_in,
          f16* __restrict__ hhi_out, f16* __restrict__ hlo_out,
          float* __restrict__ c_perm, float* __restrict__ h_final,
          const float* __restrict__ maxm_p, int s) {
  __shared__ uint4 sLds[5120];      // 80 KB

  const int tid = threadIdx.x;
  const int lane = tid & 63;
  const int w = tid >> 6;
  const int rg = w >> 2, jg = (w >> 1) & 1, gg = w & 1;
  const int bid = blockIdx.x;
  const int mt = bid >> 4, jt = bid & 15;
  const int m0 = mt * 32;

  // wave-frag bias (added into acc before sG write)
  float biasv[2];
#pragma unroll
  for (int gs = 0; gs < 2; gs++)
    biasv[gs] = bsum[(gg * 2 + gs) * 512 + jt * 32 + jg * 16 + (lane & 15)];

  const int nch = (s == 0) ? 1 : 9;

  // ---- prologue: B chunk 0 + A chunk 0 (x|a|t split hi/lo) ----
  {
#pragma unroll
    for (int i = 0; i < 4; i++)
      sLds[1024 + tid + i * 512] = wsw[(size_t)(jt * 9 + 0) * 2048 + tid + i * 512];

    const float ts = (float)s / (*maxm_p);
    size_t srow = (size_t)(199 - s) * 1024 + m0;
    int row = tid >> 4, kq = (tid & 15) * 4;     // 32 rows x 16 kq-groups
    float v[4];
#pragma unroll
    for (int e = 0; e < 4; e++) {
      int k = kq + e;
      if (k < 48)      v[e] = x[(srow + row) * 48 + k];
      else if (k < 63) v[e] = a[(srow + row) * 15 + (k - 48)];
      else             v[e] = ts;
    }
    f16x4 hi, lo;
#pragma unroll
    for (int e = 0; e < 4; e++) {
      f16 h8 = (f16)v[e];
      hi[e] = h8; lo[e] = (f16)(v[e] - (float)h8);
    }
    int rg2 = row >> 4, ks2 = kq >> 5;
    int ln = (((kq & 31) >> 3) << 4) | (row & 15);
    int half = (kq >> 2) & 1;                    // which 8B of the 16B slot
    int Lhi = (rg2 * 2 + ks2) * 2;               // p=0 line; p=1 at +1
    char* base = (char*)sLds;
    *(f16x4*)(base + ((Lhi * 64 + ln) * 16 + half * 8)) = hi;
    *(f16x4*)(base + (((Lhi + 1) * 64 + ln) * 16 + half * 8)) = lo;
  }
  __syncthreads();

  f32x4 acc[2];
  acc[0] = (f32x4){0.f, 0.f, 0.f, 0.f};
  acc[1] = (f32x4){0.f, 0.f, 0.f, 0.f};

  int cur = 0;
  for (int ch = 0; ch < nch; ch++) {
    const bool pref = (ch + 1 < nch);
    uint4 pa, pb[4];
    if (pref) {
      {                                          // A: h chunk ch, 1 uint4/thr
        int L = tid >> 6, ln = tid & 63;
        int rg2 = L >> 2, ks2 = (L >> 1) & 1, p2 = L & 1;
        const f16* pl = p2 ? hlo_in : hhi_in;
        size_t ad = (size_t)(m0 + rg2 * 16 + (ln & 15)) * 512 +
                    ch * 64 + ks2 * 32 + (ln >> 4) * 8;
        pa = *(const uint4*)&pl[ad];
      }
#pragma unroll
      for (int i = 0; i < 4; i++)                // B: chunk ch+1 image
        pb[i] = wsw[(size_t)(jt * 9 + ch + 1) * 2048 + tid + i * 512];
    }

    const int aB = cur * 512;
    const int bB = 1024 + cur * 2048;
#pragma unroll
    for (int ks = 0; ks < 2; ks++) {
      int aL = aB + ((rg * 2 + ks) * 2) * 64 + lane;
      f16x8 Ah = *(const f16x8*)&sLds[aL];
      f16x8 Al = *(const f16x8*)&sLds[aL + 64];
      __builtin_amdgcn_s_setprio(1);
#pragma unroll
      for (int gs = 0; gs < 2; gs++) {
        int g = gg * 2 + gs;
        int bL = bB + (((g * 2 + jg) * 2 + ks) * 2) * 64 + lane;
        f16x8 Bh = *(const f16x8*)&sLds[bL];
        f16x8 Bl = *(const f16x8*)&sLds[bL + 64];
        acc[gs] = __builtin_amdgcn_mfma_f32_16x16x32_f16(Ah, Bh, acc[gs], 0, 0, 0);
        acc[gs] = __builtin_amdgcn_mfma_f32_16x16x32_f16(Al, Bh, acc[gs], 0, 0, 0);
        acc[gs] = __builtin_amdgcn_mfma_f32_16x16x32_f16(Ah, Bl, acc[gs], 0, 0, 0);
      }
      __builtin_amdgcn_s_setprio(0);
    }

    if (pref) {
      sLds[(cur ^ 1) * 512 + tid] = pa;          // A region linear
#pragma unroll
      for (int i = 0; i < 4; i++)
        sLds[1024 + (cur ^ 1) * 2048 + tid + i * 512] = pb[i];
    }
    __syncthreads();
    cur ^= 1;
  }

  // ---- acc(+bias) -> sG in B0 region (C/D: col=lane&15, row=(lane>>4)*4+i) --
  {
    float* sGf = (float*)&sLds[1024];            // 32 x 133 fp32
#pragma unroll
    for (int gs = 0; gs < 2; gs++) {
      int col = (gg * 2 + gs) * 32 + jg * 16 + (lane & 15);
#pragma unroll
      for (int i = 0; i < 4; i++) {
        int row = rg * 16 + (lane >> 4) * 4 + i;
        sGf[row * 133 + col] = acc[gs][i] + biasv[gs];
      }
    }
  }
  __syncthreads();

  // ---- cell: 2 elems/thread; c in c_perm (thread-linear); h hi/lo planes ----
  {
    const float* sGf = (const float*)&sLds[1024];
    int m = tid >> 4, jp = (tid & 15) * 2;
    f32x2 cc = {0.f, 0.f};
    if (s > 0) cc = *(const f32x2*)&c_perm[(size_t)(bid * 512 + tid) * 2];
#pragma unroll
    for (int u = 0; u < 2; u++) {
      int jj = jp + u;
      float gi = sGf[m * 133 +       jj];
      float gf = sGf[m * 133 +  32 + jj];
      float gG = sGf[m * 133 +  64 + jj];
      float go = sGf[m * 133 +  96 + jj];
      float c = sigf(gf) * cc[u] + sigf(gi) * tanhf(gG);
      cc[u] = c;
      float h = sigf(go) * tanhf(c);
      size_t r = (size_t)(m0 + m) * 512 + jt * 32 + jj;
      f16 h8 = (f16)h;
      hhi_out[r] = h8;
      hlo_out[r] = (f16)(h - (float)h8);
      if (s == 199) h_final[r] = h;
    }
    *(f32x2*)&c_perm[(size_t)(bid * 512 + tid) * 2] = cc;
  }
}

// ============================= max(m) =======================================
__global__ void __launch_bounds__(1024)
maxm_kernel(const float* __restrict__ mv, float* __restrict__ out) {
  __shared__ float red[1024];
  int tid = threadIdx.x;
  float mx = -3.0e38f;
  for (int i = tid; i < 200 * 1024; i += 1024) mx = fmaxf(mx, mv[i]);
  red[tid] = mx;
  __syncthreads();
  for (int s = 512; s > 0; s >>= 1) {
    if (tid < s) red[tid] = fmaxf(red[tid], red[tid + s]);
    __syncthreads();
  }
  if (tid == 0) *out = red[0];
}

// ============ head layer 1: z = tanh(h @ {lw1,vw1}^T + b1) ==================
__global__ void __launch_bounds__(256, 2)
head1_valu(const float* __restrict__ h, const float* __restrict__ lw1,
           const float* __restrict__ lb1, const float* __restrict__ vw1,
           const float* __restrict__ vb1, float* __restrict__ z) {
  __shared__ float sAT[64 * 68];
  const int tid = threadIdx.x;
  const int rg = tid & 15;
  const int cgrp = tid >> 4;
  const int bid = blockIdx.x;
  const int mt = bid & 15, nt = bid >> 4;
  const int m0 = mt * 64;
  const int nb = nt * 64 + cgrp * 4;

  const float* wr[4];
  float bias[4];
  int hdv[4], wnv[4], valid[4];
#pragma unroll
  for (int c = 0; c < 4; c++) {
    int n = nb + c;
    valid[c] = (n < 1026);
    int hd = valid[c] ? (n >= 513) : 0;
    int wn = valid[c] ? (n - hd * 513) : 0;
    hdv[c] = hd; wnv[c] = wn;
    wr[c] = (hd ? vw1 : lw1) + (size_t)wn * 512;
    bias[c] = valid[c] ? (hd ? vb1[wn] : lb1[wn]) : 0.f;
  }

  float acc[4][4];
#pragma unroll
  for (int i = 0; i < 4; i++)
#pragma unroll
    for (int c = 0; c < 4; c++) acc[i][c] = 0.f;

  for (int ch = 0; ch < 8; ch++) {
    int k0 = ch * 64;
    for (int idx = tid; idx < 4096; idx += 256) {
      int row = idx >> 6, k = idx & 63;
      sAT[k * 68 + row] = h[(size_t)(m0 + row) * 512 + k0 + k];
    }
    __syncthreads();
#pragma unroll 4
    for (int k4 = 0; k4 < 16; k4++) {
      f32x4 wv[4];
#pragma unroll
      for (int c = 0; c < 4; c++)
        wv[c] = *(const f32x4*)(wr[c] + k0 + k4 * 4);
      f32x4 rv[4];
#pragma unroll
      for (int kk = 0; kk < 4; kk++)
        rv[kk] = *(const f32x4*)&sAT[(k4 * 4 + kk) * 68 + rg * 4];
#pragma unroll
      for (int kk = 0; kk < 4; kk++)
#pragma unroll
        for (int c = 0; c < 4; c++) {
          acc[0][c] += rv[kk][0] * wv[c][kk];
          acc[1][c] += rv[kk][1] * wv[c][kk];
          acc[2][c] += rv[kk][2] * wv[c][kk];
          acc[3][c] += rv[kk][3] * wv[c][kk];
        }
    }
    __syncthreads();
  }
#pragma unroll
  for (int c = 0; c < 4; c++) {
    if (!valid[c]) continue;
#pragma unroll
    for (int i = 0; i < 4; i++) {
      int m = m0 + rg * 4 + i;
      z[(size_t)hdv[c] * 1024 * 520 + (size_t)m * 520 + wnv[c]] =
          tanhf(acc[i][c] + bias[c]);
    }
  }
}

// ============ head layer 2: out = tanh(z @ {lw2,vw2}^T + b2) ================
__global__ void __launch_bounds__(256)
head2_valu(const float* __restrict__ z, const float* __restrict__ lw2,
           const float* __restrict__ lb2, const float* __restrict__ vw2,
           const float* __restrict__ vb2, float* __restrict__ out) {
  __shared__ float sZ[8 * 133];
  __shared__ float sW[32 * 133];
  const int tid = threadIdx.x;
  const int bid = blockIdx.x;
  const int gr0 = bid * 8;
  const int hd = gr0 >> 10;
  const int b0 = gr0 & 1023;
  const float* w2 = hd ? vw2 : lw2;
  const float* b2 = hd ? vb2 : lb2;
  const float* zh = z + (size_t)hd * 1024 * 520;
  const int rloc = tid >> 5, col = tid & 31;
  float acc = 0.f;

  for (int ch = 0; ch < 5; ch++) {
    int kc = ch * 128;
    for (int idx = tid; idx < 1024; idx += 256) {
      int row = idx >> 7, k = idx & 127;
      int kk = kc + k;
      sZ[row * 133 + k] = (kk < 513) ? zh[(size_t)(b0 + row) * 520 + kk] : 0.f;
    }
    for (int idx = tid; idx < 4096; idx += 256) {
      int row = idx >> 7, k = idx & 127;
      int kk = kc + k;
      sW[row * 133 + k] = (kk < 513) ? w2[(size_t)row * 513 + kk] : 0.f;
    }
    __syncthreads();
#pragma unroll 8
    for (int k = 0; k < 128; k++)
      acc += sZ[rloc * 133 + k] * sW[col * 133 + k];
    __syncthreads();
  }
  out[(size_t)hd * 32768 + (size_t)(b0 + rloc) * 32 + col] = tanhf(acc + b2[col]);
}

// ============================================================================
extern "C" void kernel_launch(void* const* d_in, const int* in_sizes, int n_in,
                              void* d_out, int out_size, void* d_ws, size_t ws_size,
                              hipStream_t stream) {
  (void)in_sizes; (void)n_in; (void)out_size; (void)ws_size;
  const float* x    = (const float*)d_in[0];
  const float* a    = (const float*)d_in[1];
  const float* mm   = (const float*)d_in[2];
  const float* w_ih = (const float*)d_in[3];
  const float* w_hh = (const float*)d_in[4];
  const float* b_ih = (const float*)d_in[5];
  const float* b_hh = (const float*)d_in[6];
  const float* lw1  = (const float*)d_in[7];
  const float* lb1  = (const float*)d_in[8];
  const float* lw2  = (const float*)d_in[9];
  const float* lb2  = (const float*)d_in[10];
  const float* vw1  = (const float*)d_in[11];
  const float* vb1  = (const float*)d_in[12];
  const float* vw2  = (const float*)d_in[13];
  const float* vb2  = (const float*)d_in[14];

  char* wsb = (char*)d_ws;
  float* maxm   = (float*)wsb;                       // 256 B
  float* c_perm = (float*)(wsb + 512);               // 2 MB (aliases z: LSTM-only)
  float* z      = (float*)(wsb + 512);               // 2x1024x520 f32 (heads)
  float* h_fin  = (float*)(wsb + 4260352);           // 1024x512 f32
  uint4* wsw    = (uint4*)(wsb + 6357504);           // 294912 uint4 = 4.5 MB
  float* bsum   = (float*)(wsb + 11076096);          // 2048 f32
  f16*   hhi    = (f16*)(wsb + 11084288);            // [2][1024][512] f16
  f16*   hlo    = (f16*)(wsb + 13181440);            // [2][1024][512] f16

  maxm_kernel<<<1, 1024, 0, stream>>>(mm, maxm);
  wprep_kernel<<<1152, 256, 0, stream>>>(w_ih, w_hh, wsw, b_ih, b_hh, bsum);

  for (int s = 0; s < 200; s++) {
    const int bin = s & 1, bout = bin ^ 1;
    lstm_step<<<512, 512, 0, stream>>>(
        x, a, wsw, bsum,
        hhi + (size_t)bin * 1024 * 512, hlo + (size_t)bin * 1024 * 512,
        hhi + (size_t)bout * 1024 * 512, hlo + (size_t)bout * 1024 * 512,
        c_perm, h_fin, maxm, s);
  }

  head1_valu<<<272, 256, 0, stream>>>(h_fin, lw1, lb1, vw1, vb1, z);
  head2_valu<<<256, 256, 0, stream>>>(z, lw2, lb2, vw2, vb2, (float*)d_out);
}

// Round 8
// 4754.433 us; speedup vs baseline: 1.8116x; 1.8116x over previous
//
#include <hip/hip_runtime.h>
#include <cstdint>

// ============================================================================
// EncoderLSTMReal: reverse LSTM (T=200,B=1024,H=512,IN=64) + 2 tanh-MLP heads.
// CONTRACT (R0-R8): inputs fp32 dict order; OUTPUT FLOAT32 (mu 0..32768, lv
// next); heads read fp32 h_final.
// Round-17 (R8): persistent coop LSTM, FENCE-FREE, h via LLC atomics.
//   Ledger: R5 persistent failed on per-step __threadfence (L2 wb+inv every
//   step: FETCH 1.84 GB, 85% idle). R6/R7 per-step launches: kernel boundary
//   invalidates L2 => ~9 MB/step restream, 35-42 us/step. Weights never
//   change => must stay L2-resident across steps => persistent + no fences.
//   h is the ONLY cross-block state: moved via __hip_atomic_{load,store}
//   AGENT relaxed (emits sc0 sc1 -> bypasses L1+L2, hits die-coherent LLC;
//   correct across XCDs by ISA semantics, NO fence, NO XCD assumption).
//   h packed uint = lo16<<16|hi16 (same f16 values as R5 => same numerics).
//   c stays in VGPRs all 200 steps. wsw/x normal cached loads (L2-resident).
//   Per-mt 16-block barrier: padded LLC atomic counter, monotonic counts
//   (zeroed by wprep); __syncthreads vmcnt-drain = release; sc-loads need
//   no acquire. Body geometry = R5 (verified absmax 0.00195): grid 256 =
//   16mt x 16jt, block 512 = 8 waves (4rg x 2jg), wave = 16r x 16jj x
//   4 gates, cell in regs, wsw-preswizzled B, split-fp16 3-MFMA.
// ws: maxm@0; bar@256 (256 u32, stride-16 used); z@4096; h_fin@4263936;
//     wsw@6361088 (4.5MB); hpk@11079680 (uint[2][1024][512]); end 15273984.
// ============================================================================

typedef _Float16 f16;
typedef __attribute__((ext_vector_type(8))) _Float16 f16x8;
typedef __attribute__((ext_vector_type(8))) unsigned short u16x8;
typedef __attribute__((ext_vector_type(4))) float f32x4;

#define DEV __device__ __forceinline__

DEV float sigf(float x) { return 1.0f / (1.0f + expf(-x)); }

// ============ weight pre-swizzle + bar zero (layout as R5/R6) ===============
// wsw uint4 idx = ((jt*9 + ch)*32 + Lb)*64 + lane, Lb = ((g*2+jg)*2+ks)*2+p.
// value: 8 halves of plane p of w[n][kb..kb+7], n = g*512+jt*32+jg*16+(lane&15),
// kb = ch*64 + ks*32 + (lane>>4)*8.  (k<64 -> w_ih, else w_hh.)
__global__ void __launch_bounds__(256)
wprep_kernel(const float* __restrict__ w_ih, const float* __restrict__ w_hh,
             uint4* __restrict__ wsw, unsigned* __restrict__ bar) {
  int idx = blockIdx.x * 256 + threadIdx.x;       // 1152*256 = 294912 exact
  if (blockIdx.x == 0 && threadIdx.x < 256) bar[threadIdx.x] = 0u;
  if (idx >= 16 * 9 * 32 * 64) return;
  int jt = idx / 18432, rem = idx - jt * 18432;
  int ch = rem >> 11, r2 = rem & 2047;
  int Lb = r2 >> 6, lane = r2 & 63;
  int p = Lb & 1, ks = (Lb >> 1) & 1, jg = (Lb >> 2) & 1, g = Lb >> 3;
  int n = g * 512 + jt * 32 + jg * 16 + (lane & 15);
  int kb = ch * 64 + ks * 32 + (lane >> 4) * 8;
  f16x8 o;
#pragma unroll
  for (int e = 0; e < 8; e++) {
    int k = kb + e;
    float v = (k < 64) ? w_ih[n * 64 + k] : w_hh[(size_t)n * 512 + (k - 64)];
    f16 hi = (f16)v;
    o[e] = p ? (f16)(v - (float)hi) : hi;
  }
  wsw[idx] = *(uint4*)&o;
}

// ======================= persistent LSTM (cooperative) ======================
// grid 256 = 16 mt x 16 jt; block 512 = 8 waves = 4 rg x 2 jg.
// wave (rg,jg): rows m0+rg*16..+15, cols = 4 gates x (jt*32 + jg*16 ..+15).
// LDS buf (48 KB halves): A lines 0..15 (id=(rg2*2+ks)*2+p), B lines 16..47;
// line = 64 lanes x 8 halves, LINEAR in stage id.
__global__ void __launch_bounds__(512, 2)
lstm_persist(const float* __restrict__ x, const float* __restrict__ a,
             const uint4* __restrict__ wsw,
             const float* __restrict__ b_ih, const float* __restrict__ b_hh,
             unsigned* __restrict__ hpk, float* __restrict__ h_final,
             const float* __restrict__ maxm_p, unsigned* __restrict__ bar) {
  __shared__ unsigned short sAB[2][24576];  // [buf][ A: 8192 | B: 16384 ]

  const int tid = threadIdx.x;
  const int lane = tid & 63;
  const int w = tid >> 6;
  const int rg = w >> 1, jg = w & 1;
  const int bid = blockIdx.x;
  const int mt = bid >> 4, jt = bid & 15;
  const int m0 = mt * 64;
  const int jjcol = jt * 32 + jg * 16 + (lane & 15);

  float bias[4];
#pragma unroll
  for (int g = 0; g < 4; g++)
    bias[g] = b_ih[g * 512 + jjcol] + b_hh[g * 512 + jjcol];
  f32x4 cc = {0.f, 0.f, 0.f, 0.f};
  const float mxm = *maxm_p;

  // per-thread A-stage decode (fixed all steps): slot tid -> lines La2*2,+1
  const int a_ln = tid & 63;
  const int a_La2 = tid >> 6;                    // 0..7: (rg2,ks2)
  const int a_rg2 = a_La2 >> 1, a_ks2 = a_La2 & 1;
  const size_t a_off = (size_t)(m0 + a_rg2 * 16 + (a_ln & 15)) * 512 +
                       a_ks2 * 32 + (a_ln >> 4) * 8;

  for (int s = 0; s < 200; s++) {
    const int nch = (s == 0) ? 1 : 9;
    const int bin = s & 1;
    const unsigned* hin = hpk + (size_t)bin * 1024 * 512;
    unsigned* hout = hpk + (size_t)(bin ^ 1) * 1024 * 512;

    // ---- prologue: B chunk 0 + A chunk 0 (x|a|t split hi/lo) ----
    {
#pragma unroll
      for (int i = 0; i < 4; i++) {
        int id = tid + i * 512;
        uint4 v = wsw[(size_t)(jt * 9 + 0) * 2048 + id];
        *(uint4*)&sAB[0][8192 + id * 8] = v;
      }
      const float ts = (float)s / mxm;
      size_t srow = (size_t)(199 - s) * 1024 + m0;
      int row = tid >> 3, k8 = (tid & 7) * 8;
      float v[8];
#pragma unroll
      for (int e = 0; e < 8; e++) {
        int k = k8 + e;
        if (k < 48)      v[e] = x[(srow + row) * 48 + k];
        else if (k < 63) v[e] = a[(srow + row) * 15 + (k - 48)];
        else             v[e] = ts;
      }
      f16x8 hi, lo;
#pragma unroll
      for (int e = 0; e < 8; e++) {
        f16 h8 = (f16)v[e];
        hi[e] = h8; lo[e] = (f16)(v[e] - (float)h8);
      }
      int rg2 = row >> 4, ks2 = k8 >> 5;
      int ln = (((k8 & 31) >> 3) << 4) | (row & 15);
      int Lhi = (rg2 * 2 + ks2) * 2;
      *(f16x8*)&sAB[0][(Lhi * 64 + ln) * 8] = hi;
      *(f16x8*)&sAB[0][((Lhi + 1) * 64 + ln) * 8] = lo;
    }
    __syncthreads();

    f32x4 acc[4];
#pragma unroll
    for (int g = 0; g < 4; g++) acc[g] = (f32x4){0.f, 0.f, 0.f, 0.f};

    int cur = 0;
    for (int ch = 0; ch < nch; ch++) {
      const bool pref = (ch + 1 < nch);
      unsigned long long pa[4];
      uint4 pb[4];
      if (pref) {
        // A: h chunk ch via LLC-coherent agent atomics (bypass L1+L2)
        const unsigned* src = hin + a_off + ch * 64;
#pragma unroll
        for (int j = 0; j < 4; j++)
          pa[j] = __hip_atomic_load((const unsigned long long*)src + j,
                                    __ATOMIC_RELAXED, __HIP_MEMORY_SCOPE_AGENT);
#pragma unroll
        for (int i = 0; i < 4; i++)            // B: chunk ch+1 image (cached)
          pb[i] = wsw[(size_t)(jt * 9 + ch + 1) * 2048 + tid + i * 512];
      }

      const unsigned short* buf = sAB[cur];
#pragma unroll
      for (int ks = 0; ks < 2; ks++) {
        f16x8 Ah = *(const f16x8*)&buf[(((rg * 2 + ks) * 2 + 0) * 64 + lane) * 8];
        f16x8 Al = *(const f16x8*)&buf[(((rg * 2 + ks) * 2 + 1) * 64 + lane) * 8];
        f16x8 Bh[4], Bl[4];
#pragma unroll
        for (int g = 0; g < 4; g++) {
          int base = 8192 + ((((g * 2 + jg) * 2 + ks) * 2) * 64 + lane) * 8;
          Bh[g] = *(const f16x8*)&buf[base];
          Bl[g] = *(const f16x8*)&buf[base + 512];
        }
        __builtin_amdgcn_s_setprio(1);
#pragma unroll
        for (int g = 0; g < 4; g++)
          acc[g] = __builtin_amdgcn_mfma_f32_16x16x32_f16(Ah, Bh[g], acc[g], 0, 0, 0);
#pragma unroll
        for (int g = 0; g < 4; g++)
          acc[g] = __builtin_amdgcn_mfma_f32_16x16x32_f16(Al, Bh[g], acc[g], 0, 0, 0);
#pragma unroll
        for (int g = 0; g < 4; g++)
          acc[g] = __builtin_amdgcn_mfma_f32_16x16x32_f16(Ah, Bl[g], acc[g], 0, 0, 0);
        __builtin_amdgcn_s_setprio(0);
      }

      if (pref) {
        unsigned short* nb = sAB[cur ^ 1];
        // unpack hpk -> hi/lo A lines (bit-identical f16 values)
        u16x8 HI, LO;
#pragma unroll
        for (int e = 0; e < 8; e++) {
          unsigned int u = (unsigned int)(pa[e >> 1] >> ((e & 1) * 32));
          HI[e] = (unsigned short)(u & 0xffffu);
          LO[e] = (unsigned short)(u >> 16);
        }
        int Lhi = a_La2 * 2;
        *(u16x8*)&nb[(Lhi * 64 + a_ln) * 8] = HI;
        *(u16x8*)&nb[((Lhi + 1) * 64 + a_ln) * 8] = LO;
#pragma unroll
        for (int i = 0; i < 4; i++)
          *(uint4*)&nb[8192 + (tid + i * 512) * 8] = pb[i];
      }
      __syncthreads();
      cur ^= 1;
    }

    // ---- cell fully in registers; h -> packed uint via LLC atomics ----
#pragma unroll
    for (int i = 0; i < 4; i++) {
      float gi = acc[0][i] + bias[0];
      float gf = acc[1][i] + bias[1];
      float gg = acc[2][i] + bias[2];
      float go = acc[3][i] + bias[3];
      float c = sigf(gf) * cc[i] + sigf(gi) * tanhf(gg);
      cc[i] = c;
      float h = sigf(go) * tanhf(c);
      size_t r = (size_t)(m0 + rg * 16 + (lane >> 4) * 4 + i) * 512 + jjcol;
      f16 h8 = (f16)h;
      f16 l8 = (f16)(h - (float)h8);
      unsigned pk = ((unsigned)__builtin_bit_cast(unsigned short, l8) << 16) |
                    (unsigned)__builtin_bit_cast(unsigned short, h8);
      __hip_atomic_store(&hout[r], pk, __ATOMIC_RELAXED, __HIP_MEMORY_SCOPE_AGENT);
      if (s == 199) h_final[r] = h;
    }

    // ---- per-mt 16-block barrier: LLC atomic counter, monotonic, NO fence --
    __syncthreads();                    // emits vmcnt(0) drain: stores at LLC
    if (tid == 0) {
      __hip_atomic_fetch_add(&bar[mt * 16], 1u,
                             __ATOMIC_RELAXED, __HIP_MEMORY_SCOPE_AGENT);
      unsigned target = 16u * (unsigned)(s + 1);
      while (__hip_atomic_load(&bar[mt * 16], __ATOMIC_RELAXED,
                               __HIP_MEMORY_SCOPE_AGENT) < target)
        __builtin_amdgcn_s_sleep(2);
    }
    __syncthreads();
  }
}

// ============================= max(m) =======================================
__global__ void __launch_bounds__(1024)
maxm_kernel(const float* __restrict__ mv, float* __restrict__ out) {
  __shared__ float red[1024];
  int tid = threadIdx.x;
  float mx = -3.0e38f;
  for (int i = tid; i < 200 * 1024; i += 1024) mx = fmaxf(mx, mv[i]);
  red[tid] = mx;
  __syncthreads();
  for (int s = 512; s > 0; s >>= 1) {
    if (tid < s) red[tid] = fmaxf(red[tid], red[tid + s]);
    __syncthreads();
  }
  if (tid == 0) *out = red[0];
}

// ============ head layer 1: z = tanh(h @ {lw1,vw1}^T + b1) ==================
__global__ void __launch_bounds__(256, 2)
head1_valu(const float* __restrict__ h, const float* __restrict__ lw1,
           const float* __restrict__ lb1, const float* __restrict__ vw1,
           const float* __restrict__ vb1, float* __restrict__ z) {
  __shared__ float sAT[64 * 68];
  const int tid = threadIdx.x;
  const int rg = tid & 15;
  const int cgrp = tid >> 4;
  const int bid = blockIdx.x;
  const int mt = bid & 15, nt = bid >> 4;
  const int m0 = mt * 64;
  const int nb = nt * 64 + cgrp * 4;

  const float* wr[4];
  float bias[4];
  int hdv[4], wnv[4], valid[4];
#pragma unroll
  for (int c = 0; c < 4; c++) {
    int n = nb + c;
    valid[c] = (n < 1026);
    int hd = valid[c] ? (n >= 513) : 0;
    int wn = valid[c] ? (n - hd * 513) : 0;
    hdv[c] = hd; wnv[c] = wn;
    wr[c] = (hd ? vw1 : lw1) + (size_t)wn * 512;
    bias[c] = valid[c] ? (hd ? vb1[wn] : lb1[wn]) : 0.f;
  }

  float acc[4][4];
#pragma unroll
  for (int i = 0; i < 4; i++)
#pragma unroll
    for (int c = 0; c < 4; c++) acc[i][c] = 0.f;

  for (int ch = 0; ch < 8; ch++) {
    int k0 = ch * 64;
    for (int idx = tid; idx < 4096; idx += 256) {
      int row = idx >> 6, k = idx & 63;
      sAT[k * 68 + row] = h[(size_t)(m0 + row) * 512 + k0 + k];
    }
    __syncthreads();
#pragma unroll 4
    for (int k4 = 0; k4 < 16; k4++) {
      f32x4 wv[4];
#pragma unroll
      for (int c = 0; c < 4; c++)
        wv[c] = *(const f32x4*)(wr[c] + k0 + k4 * 4);
      f32x4 rv[4];
#pragma unroll
      for (int kk = 0; kk < 4; kk++)
        rv[kk] = *(const f32x4*)&sAT[(k4 * 4 + kk) * 68 + rg * 4];
#pragma unroll
      for (int kk = 0; kk < 4; kk++)
#pragma unroll
        for (int c = 0; c < 4; c++) {
          acc[0][c] += rv[kk][0] * wv[c][kk];
          acc[1][c] += rv[kk][1] * wv[c][kk];
          acc[2][c] += rv[kk][2] * wv[c][kk];
          acc[3][c] += rv[kk][3] * wv[c][kk];
        }
    }
    __syncthreads();
  }
#pragma unroll
  for (int c = 0; c < 4; c++) {
    if (!valid[c]) continue;
#pragma unroll
    for (int i = 0; i < 4; i++) {
      int m = m0 + rg * 4 + i;
      z[(size_t)hdv[c] * 1024 * 520 + (size_t)m * 520 + wnv[c]] =
          tanhf(acc[i][c] + bias[c]);
    }
  }
}

// ============ head layer 2: out = tanh(z @ {lw2,vw2}^T + b2) ================
__global__ void __launch_bounds__(256)
head2_valu(const float* __restrict__ z, const float* __restrict__ lw2,
           const float* __restrict__ lb2, const float* __restrict__ vw2,
           const float* __restrict__ vb2, float* __restrict__ out) {
  __shared__ float sZ[8 * 133];
  __shared__ float sW[32 * 133];
  const int tid = threadIdx.x;
  const int bid = blockIdx.x;
  const int gr0 = bid * 8;
  const int hd = gr0 >> 10;
  const int b0 = gr0 & 1023;
  const float* w2 = hd ? vw2 : lw2;
  const float* b2 = hd ? vb2 : lb2;
  const float* zh = z + (size_t)hd * 1024 * 520;
  const int rloc = tid >> 5, col = tid & 31;
  float acc = 0.f;

  for (int ch = 0; ch < 5; ch++) {
    int kc = ch * 128;
    for (int idx = tid; idx < 1024; idx += 256) {
      int row = idx >> 7, k = idx & 127;
      int kk = kc + k;
      sZ[row * 133 + k] = (kk < 513) ? zh[(size_t)(b0 + row) * 520 + kk] : 0.f;
    }
    for (int idx = tid; idx < 4096; idx += 256) {
      int row = idx >> 7, k = idx & 127;
      int kk = kc + k;
      sW[row * 133 + k] = (kk < 513) ? w2[(size_t)row * 513 + kk] : 0.f;
    }
    __syncthreads();
#pragma unroll 8
    for (int k = 0; k < 128; k++)
      acc += sZ[rloc * 133 + k] * sW[col * 133 + k];
    __syncthreads();
  }
  out[(size_t)hd * 32768 + (size_t)(b0 + rloc) * 32 + col] = tanhf(acc + b2[col]);
}

// ============================================================================
extern "C" void kernel_launch(void* const* d_in, const int* in_sizes, int n_in,
                              void* d_out, int out_size, void* d_ws, size_t ws_size,
                              hipStream_t stream) {
  (void)in_sizes; (void)n_in; (void)out_size; (void)ws_size;
  const float* x    = (const float*)d_in[0];
  const float* a    = (const float*)d_in[1];
  const float* mm   = (const float*)d_in[2];
  const float* w_ih = (const float*)d_in[3];
  const float* w_hh = (const float*)d_in[4];
  const float* b_ih = (const float*)d_in[5];
  const float* b_hh = (const float*)d_in[6];
  const float* lw1  = (const float*)d_in[7];
  const float* lb1  = (const float*)d_in[8];
  const float* lw2  = (const float*)d_in[9];
  const float* lb2  = (const float*)d_in[10];
  const float* vw1  = (const float*)d_in[11];
  const float* vb1  = (const float*)d_in[12];
  const float* vw2  = (const float*)d_in[13];
  const float* vb2  = (const float*)d_in[14];

  char* wsb = (char*)d_ws;
  float*    maxm  = (float*)wsb;                     // 256 B
  unsigned* bar   = (unsigned*)(wsb + 256);          // 256 u32 (stride-16 use)
  float*    z     = (float*)(wsb + 4096);            // 2x1024x520 f32
  float*    h_fin = (float*)(wsb + 4263936);         // 1024x512 f32
  uint4*    wsw   = (uint4*)(wsb + 6361088);         // 294912 uint4 = 4.5 MB
  unsigned* hpk   = (unsigned*)(wsb + 11079680);     // [2][1024][512] uint

  maxm_kernel<<<1, 1024, 0, stream>>>(mm, maxm);
  wprep_kernel<<<1152, 256, 0, stream>>>(w_ih, w_hh, wsw, bar);

  {
    const float* xa = x; const float* aa = a;
    const uint4* wswa = wsw;
    const float* biha = b_ih; const float* bhha = b_hh;
    unsigned* hpka = hpk;
    float* hfa = h_fin; const float* mxa = maxm;
    unsigned* bara = bar;
    void* kargs[] = {&xa, &aa, &wswa, &biha, &bhha,
                     &hpka, &hfa, &mxa, &bara};
    hipLaunchCooperativeKernel((void*)lstm_persist, dim3(256), dim3(512),
                               kargs, 0, stream);
  }

  head1_valu<<<272, 256, 0, stream>>>(h_fin, lw1, lb1, vw1, vb1, z);
  head2_valu<<<256, 256, 0, stream>>>(z, lw2, lb2, vw2, vb2, (float*)d_out);
}